// Round 8
// baseline (102.458 us; speedup 1.0000x reference)
//
#include <hip/hip_runtime.h>
#include <math.h>

#define TT 8192
#define DD 4096

typedef float  f32x4  __attribute__((ext_vector_type(4)));
typedef short  bf16x8 __attribute__((ext_vector_type(8)));
typedef unsigned int u32;

// ---------------- Kernel P: split weights into 3 bf16 planes, frag-ordered ----------------
// wfrag word layout: ((p*128 + s)*2 + h)*256 + l*4  (uint4 per lane = 8 bf16)
// k = s*32 + (l>>4)*8 + i ; expert e = h*16 + (l&15).
__global__ __launch_bounds__(128)
void split_w(const float* __restrict__ gw1, const float* __restrict__ nw,
             u32* __restrict__ wfrag) {
  const int s = blockIdx.x;          // 128 k-steps
  const int t = threadIdx.x;
  const int h = t >> 6, l = t & 63;
  const int e = h * 16 + (l & 15);
  const float* src = ((e < 16) ? (gw1 + (size_t)e * DD) : (nw + (size_t)(e - 16) * DD))
                     + s * 32 + ((l >> 4) << 3);
  float f[8];
  *(float4*)&f[0] = *(const float4*)src;
  *(float4*)&f[4] = *(const float4*)(src + 4);
  u32 u0[8], u1[8], u2[8];
#pragma unroll
  for (int i = 0; i < 8; ++i) {
    u0[i] = __float_as_uint(f[i]);
    const float r1 = f[i] - __uint_as_float(u0[i] & 0xFFFF0000u);
    u1[i] = __float_as_uint(r1);
    const float r2 = r1 - __uint_as_float(u1[i] & 0xFFFF0000u);
    u2[i] = __float_as_uint(r2);
  }
  const size_t base = ((size_t)s * 2 + h) * 256 + l * 4;
#define PK(U) make_uint4((U[0]>>16)|(U[1]&0xFFFF0000u), (U[2]>>16)|(U[3]&0xFFFF0000u), \
                         (U[4]>>16)|(U[5]&0xFFFF0000u), (U[6]>>16)|(U[7]&0xFFFF0000u))
  *(uint4*)(wfrag + base)                 = PK(u0);
  *(uint4*)(wfrag + base + 128 * 512)     = PK(u1);   // plane stride = 128*2*256 words
  *(uint4*)(wfrag + base + 2 * 128 * 512) = PK(u2);
#undef PK
}

// ---------------- Kernel M: fused GEMM at 32 waves/CU ----------------
// 256 blocks x 16 waves (1024 thr). Wave v: k-slice w=v&7, row-group m=v>>3; block = 32 rows.
// Inner loop is R1's verbatim (plain x float4 loads, plain B loads) -- known numerics,
// VGPR=60 <= 64 so 8 waves/SIMD is HW-legal. LDS trimmed to 33 KB => 2 blocks/CU
// => 32 waves/CU, 2x every prior round. The ONLY variable changed vs R1/R6 is occupancy.
__global__ __launch_bounds__(1024, 8)
void gate_mega(const float* __restrict__ x, const u32* __restrict__ wfrag,
               const float* __restrict__ noise, const float* __restrict__ gw2,
               float* __restrict__ out, float* __restrict__ part2) {
  __shared__ float red[8][1024];     // 32 KB: [slice][m*512 + e*16 + row]
  __shared__ float sg2[256];
  const int t = threadIdx.x;
  const int v = t >> 6, l = t & 63;
  const int w = v & 7;               // k-slice (512 k)
  const int m = v >> 3;              // row-group (16 rows)
  const int rt = blockIdx.x;         // 32-row tile 0..255
  if (t < 256) sg2[t] = gw2[t];

  const int r = l & 15, c = l >> 4;
  const float* xp = x + (size_t)(rt * 32 + m * 16 + r) * DD + w * 512 + (c << 3);
  const u32* wfl = wfrag + (size_t)l * 4 + (size_t)(w * 16) * 512;

  f32x4 ag0 = {0,0,0,0}, ag1 = ag0, ag2 = ag0, an0 = ag0, an1 = ag0, an2 = ag0;

#pragma unroll 4
  for (int sl = 0; sl < 16; ++sl) {
    float f[8];
    *(float4*)&f[0] = *(const float4*)(xp + sl * 32);
    *(float4*)&f[4] = *(const float4*)(xp + sl * 32 + 4);

    const u32* wb = wfl + (size_t)sl * 512;
    const bf16x8 bg0 = *(const bf16x8*)(wb);
    const bf16x8 bn0 = *(const bf16x8*)(wb + 256);
    const bf16x8 bg1 = *(const bf16x8*)(wb + 128 * 512);
    const bf16x8 bn1 = *(const bf16x8*)(wb + 128 * 512 + 256);
    const bf16x8 bg2 = *(const bf16x8*)(wb + 2 * 128 * 512);
    const bf16x8 bn2 = *(const bf16x8*)(wb + 2 * 128 * 512 + 256);

    // exact 3-plane split (identical ops/order to prior rounds)
    u32 pk[12] __attribute__((aligned(16)));
#pragma unroll
    for (int p = 0; p < 4; ++p) {
      const float fa = f[2 * p], fb = f[2 * p + 1];
      const u32  a  = __float_as_uint(fa);
      const float ra1 = fa - __uint_as_float(a & 0xFFFF0000u);
      const u32  a1 = __float_as_uint(ra1);
      const float ra2 = ra1 - __uint_as_float(a1 & 0xFFFF0000u);
      const u32  a2 = __float_as_uint(ra2);
      const u32  b  = __float_as_uint(fb);
      const float rb1 = fb - __uint_as_float(b & 0xFFFF0000u);
      const u32  b1 = __float_as_uint(rb1);
      const float rb2 = rb1 - __uint_as_float(b1 & 0xFFFF0000u);
      const u32  b2 = __float_as_uint(rb2);
      pk[p]     = (a  >> 16) | (b  & 0xFFFF0000u);
      pk[4 + p] = (a1 >> 16) | (b1 & 0xFFFF0000u);
      pk[8 + p] = (a2 >> 16) | (b2 & 0xFFFF0000u);
    }
    const bf16x8 a0 = *(const bf16x8*)&pk[0];
    const bf16x8 a1 = *(const bf16x8*)&pk[4];
    const bf16x8 a2 = *(const bf16x8*)&pk[8];

    ag0 = __builtin_amdgcn_mfma_f32_16x16x32_bf16(a0, bg0, ag0, 0, 0, 0);
    an0 = __builtin_amdgcn_mfma_f32_16x16x32_bf16(a0, bn0, an0, 0, 0, 0);
    ag1 = __builtin_amdgcn_mfma_f32_16x16x32_bf16(a0, bg1, ag1, 0, 0, 0);
    an1 = __builtin_amdgcn_mfma_f32_16x16x32_bf16(a0, bn1, an1, 0, 0, 0);
    ag2 = __builtin_amdgcn_mfma_f32_16x16x32_bf16(a1, bg0, ag2, 0, 0, 0);
    an2 = __builtin_amdgcn_mfma_f32_16x16x32_bf16(a1, bn0, an2, 0, 0, 0);
    ag0 = __builtin_amdgcn_mfma_f32_16x16x32_bf16(a0, bg2, ag0, 0, 0, 0);
    an0 = __builtin_amdgcn_mfma_f32_16x16x32_bf16(a0, bn2, an0, 0, 0, 0);
    ag1 = __builtin_amdgcn_mfma_f32_16x16x32_bf16(a1, bg1, ag1, 0, 0, 0);
    an1 = __builtin_amdgcn_mfma_f32_16x16x32_bf16(a1, bn1, an1, 0, 0, 0);
    ag2 = __builtin_amdgcn_mfma_f32_16x16x32_bf16(a2, bg0, ag2, 0, 0, 0);
    an2 = __builtin_amdgcn_mfma_f32_16x16x32_bf16(a2, bn0, an2, 0, 0, 0);
  }

  const f32x4 cg = ag0 + ag1 + ag2;
  const f32x4 cn = an0 + an1 + an2;
  // C/D: col(lane&15)=expert, row=(lane>>4)*4+reg [m89]. Store as [m*512 + e*16 + row].
#pragma unroll
  for (int j = 0; j < 4; ++j) {
    red[w][m * 512 + r * 16 + (c * 4 + j)]        = cg[j];
    red[w][m * 512 + (16 + r) * 16 + (c * 4 + j)] = cn[j];
  }
  __syncthreads();
  // 1024-thread reduce across the 8 k-slices, ascending order (bitwise-stable).
  {
    float s = red[0][t];
#pragma unroll
    for (int ww = 1; ww < 8; ++ww) s += red[ww][t];
    red[0][t] = s;   // column-exclusive per thread: no race
  }
  __syncthreads();

  if (t < 32) {
    const int mg = t >> 4, rr = t & 15;
    const int row = rt * 32 + t;
    float dot[32];
#pragma unroll
    for (int e = 0; e < 32; ++e) dot[e] = red[0][mg * 512 + e * 16 + rr];
    float h[16];
#pragma unroll
    for (int e = 0; e < 16; ++e) h[e] = tanhf(dot[e]);
    float lg[16], nc[16], ln[16], lo[16];
#pragma unroll
    for (int j = 0; j < 16; ++j) {
      float s = 0.f;
#pragma unroll
      for (int e = 0; e < 16; ++e) s = fmaf(h[e], sg2[j * 16 + e], s);
      lg[j] = s;
      const float vv = dot[16 + j];
      nc[j] = fmaxf(vv, 0.f) + log1pf(expf(-fabsf(vv))) + 0.01f;
      ln[j] = noise[(size_t)row * 16 + j] * nc[j];
      lo[j] = lg[j] + ln[j];
    }
    int i0 = 0; float m0 = lo[0];
#pragma unroll
    for (int j = 1; j < 16; ++j) if (lo[j] > m0) { m0 = lo[j]; i0 = j; }
    int i1 = -1; float m1 = -1e30f;
#pragma unroll
    for (int j = 0; j < 16; ++j) if (j != i0 && lo[j] > m1) { m1 = lo[j]; i1 = j; }
    float m2 = -1e30f;
#pragma unroll
    for (int j = 0; j < 16; ++j) if (j != i0 && j != i1 && lo[j] > m2) m2 = lo[j];

    const float e1 = expf(m1 - m0);
    const float s0 = 1.f / (1.f + e1);
    const float s1 = e1 / (1.f + e1);
    out[(size_t)row * 2]             = (float)i0;
    out[(size_t)row * 2 + 1]         = (float)i1;
    out[16384 + (size_t)row * 2]     = s0;
    out[16384 + (size_t)row * 2 + 1] = s1;

    float cacc[32];
#pragma unroll
    for (int j = 0; j < 16; ++j) {
      cacc[j] = (j == i0) ? s0 : ((j == i1) ? s1 : 0.f);
      const bool in = ln[j] > m2;
      const float thr = in ? m2 : m1;
      const float z = (lg[j] - thr) / nc[j];
      cacc[16 + j] = 0.5f * (1.f + erff(z * 0.70710678118654752f));
    }
    // reduce the 32 loss partials across each 16-row group (xor<16 stays in-group)
#pragma unroll
    for (int off = 1; off < 16; off <<= 1) {
#pragma unroll
      for (int k = 0; k < 32; ++k) cacc[k] += __shfl_xor(cacc[k], off, 16);
    }
    // group g = rt*2 + mg keeps the exact part2 layout/order of prior rounds
    const int g = rt * 2 + mg;
    float v0 = 0.f, v1 = 0.f;
#pragma unroll
    for (int k = 0; k < 16; ++k) if (rr == k) { v0 = cacc[k]; v1 = cacc[16 + k]; }
    part2[(size_t)g * 32 + rr]      = v0;
    part2[(size_t)g * 32 + 16 + rr] = v1;
  }
}

// ---------------- Kernel C: reduce per-block partials -> cv^2 loss ----------------
__global__ __launch_bounds__(256)
void gate_loss_k(const float* __restrict__ part2, float* __restrict__ out) {
  __shared__ float sred[8][32];
  const int t = threadIdx.x;        // 256
  const int k = t & 31, s = t >> 5; // expert, block-slice (8 slices of 64 groups)
  float acc = 0.f;
#pragma unroll 8
  for (int i = 0; i < 64; ++i) acc += part2[(size_t)(s * 64 + i) * 32 + k];
  sred[s][k] = acc;
  __syncthreads();
  if (t == 0) {
    float res = 0.f;
    for (int g = 0; g < 2; ++g) {
      float vals[16];
      float mu = 0.f;
      for (int j = 0; j < 16; ++j) {
        float s2 = 0.f;
        for (int ss = 0; ss < 8; ++ss) s2 += sred[ss][g * 16 + j];
        vals[j] = s2;
        mu += s2;
      }
      mu *= (1.f / 16.f);
      float var = 0.f;
      for (int j = 0; j < 16; ++j) { const float d = vals[j] - mu; var += d * d; }
      var *= (1.f / 15.f);
      res += var / (mu * mu + 1e-10f);
    }
    out[32768] = res * 0.01f;
  }
}

extern "C" void kernel_launch(void* const* d_in, const int* in_sizes, int n_in,
                              void* d_out, int out_size, void* d_ws, size_t ws_size,
                              hipStream_t stream) {
  const float* x     = (const float*)d_in[0];
  const float* gw1   = (const float*)d_in[1];
  const float* gw2   = (const float*)d_in[2];
  const float* nw    = (const float*)d_in[3];
  const float* noise = (const float*)d_in[4];
  float* out   = (float*)d_out;
  u32*   wfrag = (u32*)d_ws;                                   // 768 KB, fully written
  float* part2 = (float*)((char*)d_ws + (size_t)768 * 1024);   // 64 KB, fully written
  split_w<<<128, 128, 0, stream>>>(gw1, nw, wfrag);
  gate_mega<<<256, 1024, 0, stream>>>(x, wfrag, noise, gw2, out, part2);
  gate_loss_k<<<1, 256, 0, stream>>>(part2, out);
}

// Round 9
// 72.798 us; speedup vs baseline: 1.4074x; 1.4074x over previous
//
#include <hip/hip_runtime.h>
#include <math.h>

#define TT 8192
#define DD 4096

typedef float  f32x4  __attribute__((ext_vector_type(4)));
typedef short  bf16x8 __attribute__((ext_vector_type(8)));
typedef unsigned int u32;

// ---------------- Kernel P: split weights into 3 bf16 planes, frag-ordered ----------------
// wfrag word layout: ((p*128 + s)*2 + h)*256 + l*4  (uint4 per lane = 8 bf16)
// k = s*32 + (l>>4)*8 + i ; expert e = h*16 + (l&15).
__global__ __launch_bounds__(128)
void split_w(const float* __restrict__ gw1, const float* __restrict__ nw,
             u32* __restrict__ wfrag) {
  const int s = blockIdx.x;          // 128 k-steps
  const int t = threadIdx.x;
  const int h = t >> 6, l = t & 63;
  const int e = h * 16 + (l & 15);
  const float* src = ((e < 16) ? (gw1 + (size_t)e * DD) : (nw + (size_t)(e - 16) * DD))
                     + s * 32 + ((l >> 4) << 3);
  float f[8];
  *(float4*)&f[0] = *(const float4*)src;
  *(float4*)&f[4] = *(const float4*)(src + 4);
  u32 u0[8], u1[8], u2[8];
#pragma unroll
  for (int i = 0; i < 8; ++i) {
    u0[i] = __float_as_uint(f[i]);
    const float r1 = f[i] - __uint_as_float(u0[i] & 0xFFFF0000u);
    u1[i] = __float_as_uint(r1);
    const float r2 = r1 - __uint_as_float(u1[i] & 0xFFFF0000u);
    u2[i] = __float_as_uint(r2);
  }
  const size_t base = ((size_t)s * 2 + h) * 256 + l * 4;
#define PK(U) make_uint4((U[0]>>16)|(U[1]&0xFFFF0000u), (U[2]>>16)|(U[3]&0xFFFF0000u), \
                         (U[4]>>16)|(U[5]&0xFFFF0000u), (U[6]>>16)|(U[7]&0xFFFF0000u))
  *(uint4*)(wfrag + base)                 = PK(u0);
  *(uint4*)(wfrag + base + 128 * 512)     = PK(u1);   // plane stride = 128*2*256 words
  *(uint4*)(wfrag + base + 2 * 128 * 512) = PK(u2);
#undef PK
}

// ---------------- Kernel M: R1 structure + NON-TEMPORAL x loads (single variable) --------
// 512 blocks x 8 waves; block owns 16 rows, wave w owns k-slice w*512.
// x marked nontemporal (zero reuse) so streaming x stops evicting wfrag from the XCD L2;
// B reads then stay L2-resident. NO pinning, NO prefetch rings -- scheduler free (R1 sched).
// Numerics bitwise-identical to R1 (same loads -> same split -> same MFMA/reduce order).
__global__ __launch_bounds__(512, 4)
void gate_mega(const float* __restrict__ x, const u32* __restrict__ wfrag,
               const float* __restrict__ noise, const float* __restrict__ gw2,
               float* __restrict__ out, float* __restrict__ part2) {
  __shared__ float red[8][512];      // [wave][e*16 + row]
  __shared__ float sg2[256];
  const int t = threadIdx.x;
  const int w = t >> 6, l = t & 63;
  const int rt = blockIdx.x;         // 16-row tile 0..511
  if (t < 256) sg2[t] = gw2[t];

  const int r = l & 15, c = l >> 4;
  const float* xp = x + (size_t)(rt * 16 + r) * DD + w * 512 + (c << 3);
  const u32* wfl = wfrag + (size_t)l * 4 + (size_t)(w * 16) * 512;

  f32x4 ag0 = {0,0,0,0}, ag1 = ag0, ag2 = ag0, an0 = ag0, an1 = ag0, an2 = ag0;

#pragma unroll 2
  for (int sl = 0; sl < 16; ++sl) {
    const f32x4 q0 = __builtin_nontemporal_load((const f32x4*)(xp + sl * 32));
    const f32x4 q1 = __builtin_nontemporal_load((const f32x4*)(xp + sl * 32 + 4));

    const u32* wb = wfl + (size_t)sl * 512;
    const bf16x8 bg0 = *(const bf16x8*)(wb);
    const bf16x8 bn0 = *(const bf16x8*)(wb + 256);
    const bf16x8 bg1 = *(const bf16x8*)(wb + 128 * 512);
    const bf16x8 bn1 = *(const bf16x8*)(wb + 128 * 512 + 256);
    const bf16x8 bg2 = *(const bf16x8*)(wb + 2 * 128 * 512);
    const bf16x8 bn2 = *(const bf16x8*)(wb + 2 * 128 * 512 + 256);

    // exact 3-plane split (identical ops/order to prior rounds)
    u32 pk[12] __attribute__((aligned(16)));
#pragma unroll
    for (int p = 0; p < 4; ++p) {
      const float fa = (p < 2 ? q0 : q1)[(p & 1) * 2];
      const float fb = (p < 2 ? q0 : q1)[(p & 1) * 2 + 1];
      const u32  a  = __float_as_uint(fa);
      const float ra1 = fa - __uint_as_float(a & 0xFFFF0000u);
      const u32  a1 = __float_as_uint(ra1);
      const float ra2 = ra1 - __uint_as_float(a1 & 0xFFFF0000u);
      const u32  a2 = __float_as_uint(ra2);
      const u32  b  = __float_as_uint(fb);
      const float rb1 = fb - __uint_as_float(b & 0xFFFF0000u);
      const u32  b1 = __float_as_uint(rb1);
      const float rb2 = rb1 - __uint_as_float(b1 & 0xFFFF0000u);
      const u32  b2 = __float_as_uint(rb2);
      pk[p]     = (a  >> 16) | (b  & 0xFFFF0000u);
      pk[4 + p] = (a1 >> 16) | (b1 & 0xFFFF0000u);
      pk[8 + p] = (a2 >> 16) | (b2 & 0xFFFF0000u);
    }
    const bf16x8 a0 = *(const bf16x8*)&pk[0];
    const bf16x8 a1 = *(const bf16x8*)&pk[4];
    const bf16x8 a2 = *(const bf16x8*)&pk[8];

    ag0 = __builtin_amdgcn_mfma_f32_16x16x32_bf16(a0, bg0, ag0, 0, 0, 0);
    an0 = __builtin_amdgcn_mfma_f32_16x16x32_bf16(a0, bn0, an0, 0, 0, 0);
    ag1 = __builtin_amdgcn_mfma_f32_16x16x32_bf16(a0, bg1, ag1, 0, 0, 0);
    an1 = __builtin_amdgcn_mfma_f32_16x16x32_bf16(a0, bn1, an1, 0, 0, 0);
    ag2 = __builtin_amdgcn_mfma_f32_16x16x32_bf16(a1, bg0, ag2, 0, 0, 0);
    an2 = __builtin_amdgcn_mfma_f32_16x16x32_bf16(a1, bn0, an2, 0, 0, 0);
    ag0 = __builtin_amdgcn_mfma_f32_16x16x32_bf16(a0, bg2, ag0, 0, 0, 0);
    an0 = __builtin_amdgcn_mfma_f32_16x16x32_bf16(a0, bn2, an0, 0, 0, 0);
    ag1 = __builtin_amdgcn_mfma_f32_16x16x32_bf16(a1, bg1, ag1, 0, 0, 0);
    an1 = __builtin_amdgcn_mfma_f32_16x16x32_bf16(a1, bn1, an1, 0, 0, 0);
    ag2 = __builtin_amdgcn_mfma_f32_16x16x32_bf16(a2, bg0, ag2, 0, 0, 0);
    an2 = __builtin_amdgcn_mfma_f32_16x16x32_bf16(a2, bn0, an2, 0, 0, 0);
  }

  const f32x4 cg = ag0 + ag1 + ag2;
  const f32x4 cn = an0 + an1 + an2;
  // C/D: col(lane&15)=expert, row=(lane>>4)*4+reg [m89]. Store as [e*16+row].
#pragma unroll
  for (int j = 0; j < 4; ++j) {
    red[w][r * 16 + (c * 4 + j)]        = cg[j];
    red[w][(16 + r) * 16 + (c * 4 + j)] = cn[j];
  }
  __syncthreads();
  // 512-thread reduce across the 8 k-slices, ascending order (bitwise-stable).
  {
    float s = red[0][t];
#pragma unroll
    for (int ww = 1; ww < 8; ++ww) s += red[ww][t];
    red[0][t] = s;   // column-exclusive per thread: no race
  }
  __syncthreads();

  if (t < 16) {
    const int row = rt * 16 + t;
    float dot[32];
#pragma unroll
    for (int e = 0; e < 32; ++e) dot[e] = red[0][e * 16 + t];
    float h[16];
#pragma unroll
    for (int e = 0; e < 16; ++e) h[e] = tanhf(dot[e]);
    float lg[16], nc[16], ln[16], lo[16];
#pragma unroll
    for (int j = 0; j < 16; ++j) {
      float s = 0.f;
#pragma unroll
      for (int e = 0; e < 16; ++e) s = fmaf(h[e], sg2[j * 16 + e], s);
      lg[j] = s;
      const float v = dot[16 + j];
      nc[j] = fmaxf(v, 0.f) + log1pf(expf(-fabsf(v))) + 0.01f;
      ln[j] = noise[(size_t)row * 16 + j] * nc[j];
      lo[j] = lg[j] + ln[j];
    }
    int i0 = 0; float m0 = lo[0];
#pragma unroll
    for (int j = 1; j < 16; ++j) if (lo[j] > m0) { m0 = lo[j]; i0 = j; }
    int i1 = -1; float m1 = -1e30f;
#pragma unroll
    for (int j = 0; j < 16; ++j) if (j != i0 && lo[j] > m1) { m1 = lo[j]; i1 = j; }
    float m2 = -1e30f;
#pragma unroll
    for (int j = 0; j < 16; ++j) if (j != i0 && j != i1 && lo[j] > m2) m2 = lo[j];

    const float e1 = expf(m1 - m0);
    const float s0 = 1.f / (1.f + e1);
    const float s1 = e1 / (1.f + e1);
    out[(size_t)row * 2]             = (float)i0;
    out[(size_t)row * 2 + 1]         = (float)i1;
    out[16384 + (size_t)row * 2]     = s0;
    out[16384 + (size_t)row * 2 + 1] = s1;

    float cacc[32];
#pragma unroll
    for (int j = 0; j < 16; ++j) {
      cacc[j] = (j == i0) ? s0 : ((j == i1) ? s1 : 0.f);
      const bool in = ln[j] > m2;
      const float thr = in ? m2 : m1;
      const float z = (lg[j] - thr) / nc[j];
      cacc[16 + j] = 0.5f * (1.f + erff(z * 0.70710678118654752f));
    }
    // reduce the 32 loss partials across the 16 row-lanes
#pragma unroll
    for (int off = 1; off < 16; off <<= 1) {
#pragma unroll
      for (int k = 0; k < 32; ++k) cacc[k] += __shfl_xor(cacc[k], off, 16);
    }
    // lane t writes partial for expert t (static selection to avoid scratch)
    float v0 = 0.f, v1 = 0.f;
#pragma unroll
    for (int k = 0; k < 16; ++k) if (t == k) { v0 = cacc[k]; v1 = cacc[16 + k]; }
    part2[(size_t)rt * 32 + t]      = v0;
    part2[(size_t)rt * 32 + 16 + t] = v1;
  }
}

// ---------------- Kernel C: reduce per-block partials -> cv^2 loss ----------------
__global__ __launch_bounds__(256)
void gate_loss_k(const float* __restrict__ part2, float* __restrict__ out) {
  __shared__ float sred[8][32];
  const int t = threadIdx.x;        // 256
  const int k = t & 31, s = t >> 5; // expert, block-slice (8 slices of 64 blocks)
  float acc = 0.f;
#pragma unroll 8
  for (int i = 0; i < 64; ++i) acc += part2[(size_t)(s * 64 + i) * 32 + k];
  sred[s][k] = acc;
  __syncthreads();
  if (t == 0) {
    float res = 0.f;
    for (int g = 0; g < 2; ++g) {
      float vals[16];
      float mu = 0.f;
      for (int j = 0; j < 16; ++j) {
        float s2 = 0.f;
        for (int ss = 0; ss < 8; ++ss) s2 += sred[ss][g * 16 + j];
        vals[j] = s2;
        mu += s2;
      }
      mu *= (1.f / 16.f);
      float var = 0.f;
      for (int j = 0; j < 16; ++j) { const float d = vals[j] - mu; var += d * d; }
      var *= (1.f / 15.f);
      res += var / (mu * mu + 1e-10f);
    }
    out[32768] = res * 0.01f;
  }
}

extern "C" void kernel_launch(void* const* d_in, const int* in_sizes, int n_in,
                              void* d_out, int out_size, void* d_ws, size_t ws_size,
                              hipStream_t stream) {
  const float* x     = (const float*)d_in[0];
  const float* gw1   = (const float*)d_in[1];
  const float* gw2   = (const float*)d_in[2];
  const float* nw    = (const float*)d_in[3];
  const float* noise = (const float*)d_in[4];
  float* out   = (float*)d_out;
  u32*   wfrag = (u32*)d_ws;                                   // 768 KB, fully written
  float* part2 = (float*)((char*)d_ws + (size_t)768 * 1024);   // 64 KB, fully written
  split_w<<<128, 128, 0, stream>>>(gw1, nw, wfrag);
  gate_mega<<<512, 512, 0, stream>>>(x, wfrag, noise, gw2, out, part2);
  gate_loss_k<<<1, 256, 0, stream>>>(part2, out);
}

// Round 10
// 60.005 us; speedup vs baseline: 1.7075x; 1.2132x over previous
//
#include <hip/hip_runtime.h>
#include <math.h>

#define TT 8192
#define DD 4096

typedef float  f32x4  __attribute__((ext_vector_type(4)));
typedef short  bf16x8 __attribute__((ext_vector_type(8)));
typedef unsigned int u32;

typedef __attribute__((address_space(3))) void        lds_vp;
typedef const __attribute__((address_space(1))) void  gbl_vp;
// async global->LDS: lane l's 16B lands at lptr + l*16 (wave-uniform lptr, per-lane src)
#define GLD(gp_, lp_) __builtin_amdgcn_global_load_lds((gbl_vp*)(gp_), (lds_vp*)(lp_), 16, 0, 0)

// ---------------- Kernel P: split weights into 3 bf16 planes, frag-ordered ----------------
// wfrag word layout: ((p*128 + s)*2 + h)*256 + l*4  (uint4 per lane = 8 bf16)
// k = s*32 + (l>>4)*8 + i ; expert e = h*16 + (l&15).
__global__ __launch_bounds__(128)
void split_w(const float* __restrict__ gw1, const float* __restrict__ nw,
             u32* __restrict__ wfrag) {
  const int s = blockIdx.x;          // 128 k-steps
  const int t = threadIdx.x;
  const int h = t >> 6, l = t & 63;
  const int e = h * 16 + (l & 15);
  const float* src = ((e < 16) ? (gw1 + (size_t)e * DD) : (nw + (size_t)(e - 16) * DD))
                     + s * 32 + ((l >> 4) << 3);
  float f[8];
  *(float4*)&f[0] = *(const float4*)src;
  *(float4*)&f[4] = *(const float4*)(src + 4);
  u32 u0[8], u1[8], u2[8];
#pragma unroll
  for (int i = 0; i < 8; ++i) {
    u0[i] = __float_as_uint(f[i]);
    const float r1 = f[i] - __uint_as_float(u0[i] & 0xFFFF0000u);
    u1[i] = __float_as_uint(r1);
    const float r2 = r1 - __uint_as_float(u1[i] & 0xFFFF0000u);
    u2[i] = __float_as_uint(r2);
  }
  const size_t base = ((size_t)s * 2 + h) * 256 + l * 4;
#define PK(U) make_uint4((U[0]>>16)|(U[1]&0xFFFF0000u), (U[2]>>16)|(U[3]&0xFFFF0000u), \
                         (U[4]>>16)|(U[5]&0xFFFF0000u), (U[6]>>16)|(U[7]&0xFFFF0000u))
  *(uint4*)(wfrag + base)                 = PK(u0);
  *(uint4*)(wfrag + base + 128 * 512)     = PK(u1);   // plane stride = 128*2*256 words
  *(uint4*)(wfrag + base + 2 * 128 * 512) = PK(u2);
#undef PK
}

// ---------------- Kernel M: R5 ring structure + FULLY-COALESCED x staging ----------------
// 512 blocks x 8 waves; block = 16 rows, wave w = k-slice w*512.
// x staged via depth-3 per-wave LDS ring (R5's verified vmcnt discipline), but each GLD
// now fetches 8 rows x 128B CONTIGUOUS (8 consecutive lanes = one row's full line ->
// 8 full lines/instruction vs prior 64 scattered sectors). Per-row 16B rotation is
// pre-swizzled into the per-lane SOURCE address (linear LDS dest, rule #21); the rotated
// ds_read spreads lanes over 8 bank-classes -> conflict-free b128.
// Same bytes -> same per-lane floats -> bitwise-identical numerics to all prior rounds.
__global__ __launch_bounds__(512, 4)
void gate_mega(const float* __restrict__ x, const u32* __restrict__ wfrag,
               const float* __restrict__ noise, const float* __restrict__ gw2,
               float* __restrict__ out, float* __restrict__ part2) {
  __shared__ __align__(16) float ldsx[8][3][512];   // 48 KB: per-wave x ring (3 steps)
  __shared__ float red[8][512];                     // 16 KB
  __shared__ float sg2[256];
  const int t = threadIdx.x;
  const int w = t >> 6, l = t & 63;
  const int rt = blockIdx.x;         // 16-row tile 0..511
  if (t < 256) sg2[t] = gw2[t];

  const int r = l & 15, c = l >> 4;
  const u32* wfl = wfrag + (size_t)l * 4 + (size_t)(w * 16) * 512;

  // --- GLD source mapping (i = 0,1 covers rows 8i..8i+7) ---
  // LDS slot of lane l = row_local (l>>3) * 32 floats + (l&7)*4 floats  (linear dest)
  // stored content L[row][s] = x[row][(s - row*4) & 31]  (16B rotation by row)
  const int row_local = l >> 3, jj = l & 7;
  const int soff = (((jj - row_local) & 7) << 2);   // floats within the 32-float band
  const float* gsrc0 = x + (size_t)(rt * 16 + row_local) * DD + w * 512 + soff;
  const float* gsrc1 = gsrc0 + (size_t)8 * DD;

  // --- rotated read offsets (per-thread constants) ---
  const int rd0 = r * 32 + (((c << 3) + (r << 2)) & 31);
  const int rd1 = r * 32 + (((c << 3) + 4 + (r << 2)) & 31);

  f32x4 ag0 = {0,0,0,0}, ag1 = ag0, ag2 = ag0, an0 = ag0, an1 = ag0, an2 = ag0;

  // prologue: prefetch steps 0,1,2 (6 GLDs in flight)
#pragma unroll
  for (int s = 0; s < 3; ++s) {
    GLD(gsrc0 + s * 32, &ldsx[w][s][0]);
    GLD(gsrc1 + s * 32, &ldsx[w][s][256]);
  }

#pragma unroll
  for (int sl = 0; sl < 16; ++sl) {
    // retire exactly step sl's two GLDs (R5's verified discipline)
    if (sl <= 13)      asm volatile("s_waitcnt vmcnt(4)" ::: "memory");
    else if (sl == 14) asm volatile("s_waitcnt vmcnt(2)" ::: "memory");
    else               asm volatile("s_waitcnt vmcnt(0)" ::: "memory");

    const float* xb = &ldsx[w][sl % 3][0];
    const f32x4 q0 = *(const f32x4*)(xb + rd0);
    const f32x4 q1 = *(const f32x4*)(xb + rd1);

    // B frags (issued after ds_reads, consumed by this iteration's MFMAs)
    const u32* wb = wfl + (size_t)sl * 512;
    const bf16x8 bg0 = *(const bf16x8*)(wb);
    const bf16x8 bn0 = *(const bf16x8*)(wb + 256);
    const bf16x8 bg1 = *(const bf16x8*)(wb + 128 * 512);
    const bf16x8 bn1 = *(const bf16x8*)(wb + 128 * 512 + 256);
    const bf16x8 bg2 = *(const bf16x8*)(wb + 2 * 128 * 512);
    const bf16x8 bn2 = *(const bf16x8*)(wb + 2 * 128 * 512 + 256);

    // exact 3-plane split (identical ops/order to prior rounds)
    u32 pk[12] __attribute__((aligned(16)));
#pragma unroll
    for (int p = 0; p < 4; ++p) {
      const float fa = (p < 2 ? q0 : q1)[(p & 1) * 2];
      const float fb = (p < 2 ? q0 : q1)[(p & 1) * 2 + 1];
      const u32  a  = __float_as_uint(fa);
      const float ra1 = fa - __uint_as_float(a & 0xFFFF0000u);
      const u32  a1 = __float_as_uint(ra1);
      const float ra2 = ra1 - __uint_as_float(a1 & 0xFFFF0000u);
      const u32  a2 = __float_as_uint(ra2);
      const u32  b  = __float_as_uint(fb);
      const float rb1 = fb - __uint_as_float(b & 0xFFFF0000u);
      const u32  b1 = __float_as_uint(rb1);
      const float rb2 = rb1 - __uint_as_float(b1 & 0xFFFF0000u);
      const u32  b2 = __float_as_uint(rb2);
      pk[p]     = (a  >> 16) | (b  & 0xFFFF0000u);
      pk[4 + p] = (a1 >> 16) | (b1 & 0xFFFF0000u);
      pk[8 + p] = (a2 >> 16) | (b2 & 0xFFFF0000u);
    }
    const bf16x8 a0 = *(const bf16x8*)&pk[0];
    const bf16x8 a1 = *(const bf16x8*)&pk[4];
    const bf16x8 a2 = *(const bf16x8*)&pk[8];

    // ds_reads of this buffer retired -> safe to re-target it for step sl+3.
    // GLDs issued AFTER B loads so the compiler's B-wait (vmcnt(2)) keeps them in flight.
    asm volatile("s_waitcnt lgkmcnt(0)" ::: "memory");
    if (sl + 3 < 16) {
      GLD(gsrc0 + (sl + 3) * 32, &ldsx[w][sl % 3][0]);
      GLD(gsrc1 + (sl + 3) * 32, &ldsx[w][sl % 3][256]);
    }

    ag0 = __builtin_amdgcn_mfma_f32_16x16x32_bf16(a0, bg0, ag0, 0, 0, 0);
    an0 = __builtin_amdgcn_mfma_f32_16x16x32_bf16(a0, bn0, an0, 0, 0, 0);
    ag1 = __builtin_amdgcn_mfma_f32_16x16x32_bf16(a0, bg1, ag1, 0, 0, 0);
    an1 = __builtin_amdgcn_mfma_f32_16x16x32_bf16(a0, bn1, an1, 0, 0, 0);
    ag2 = __builtin_amdgcn_mfma_f32_16x16x32_bf16(a1, bg0, ag2, 0, 0, 0);
    an2 = __builtin_amdgcn_mfma_f32_16x16x32_bf16(a1, bn0, an2, 0, 0, 0);
    ag0 = __builtin_amdgcn_mfma_f32_16x16x32_bf16(a0, bg2, ag0, 0, 0, 0);
    an0 = __builtin_amdgcn_mfma_f32_16x16x32_bf16(a0, bn2, an0, 0, 0, 0);
    ag1 = __builtin_amdgcn_mfma_f32_16x16x32_bf16(a1, bg1, ag1, 0, 0, 0);
    an1 = __builtin_amdgcn_mfma_f32_16x16x32_bf16(a1, bn1, an1, 0, 0, 0);
    ag2 = __builtin_amdgcn_mfma_f32_16x16x32_bf16(a2, bg0, ag2, 0, 0, 0);
    an2 = __builtin_amdgcn_mfma_f32_16x16x32_bf16(a2, bn0, an2, 0, 0, 0);
  }

  const f32x4 cg = ag0 + ag1 + ag2;
  const f32x4 cn = an0 + an1 + an2;
  // C/D: col(lane&15)=expert, row=(lane>>4)*4+reg [m89]. Store as [e*16+row].
#pragma unroll
  for (int j = 0; j < 4; ++j) {
    red[w][r * 16 + (c * 4 + j)]        = cg[j];
    red[w][(16 + r) * 16 + (c * 4 + j)] = cn[j];
  }
  __syncthreads();
  // 512-thread reduce across the 8 k-slices, ascending order (bitwise-stable).
  {
    float s = red[0][t];
#pragma unroll
    for (int ww = 1; ww < 8; ++ww) s += red[ww][t];
    red[0][t] = s;   // column-exclusive per thread: no race
  }
  __syncthreads();

  if (t < 16) {
    const int row = rt * 16 + t;
    float dot[32];
#pragma unroll
    for (int e = 0; e < 32; ++e) dot[e] = red[0][e * 16 + t];
    float h[16];
#pragma unroll
    for (int e = 0; e < 16; ++e) h[e] = tanhf(dot[e]);
    float lg[16], nc[16], ln[16], lo[16];
#pragma unroll
    for (int j = 0; j < 16; ++j) {
      float s = 0.f;
#pragma unroll
      for (int e = 0; e < 16; ++e) s = fmaf(h[e], sg2[j * 16 + e], s);
      lg[j] = s;
      const float v = dot[16 + j];
      nc[j] = fmaxf(v, 0.f) + log1pf(expf(-fabsf(v))) + 0.01f;
      ln[j] = noise[(size_t)row * 16 + j] * nc[j];
      lo[j] = lg[j] + ln[j];
    }
    int i0 = 0; float m0 = lo[0];
#pragma unroll
    for (int j = 1; j < 16; ++j) if (lo[j] > m0) { m0 = lo[j]; i0 = j; }
    int i1 = -1; float m1 = -1e30f;
#pragma unroll
    for (int j = 0; j < 16; ++j) if (j != i0 && lo[j] > m1) { m1 = lo[j]; i1 = j; }
    float m2 = -1e30f;
#pragma unroll
    for (int j = 0; j < 16; ++j) if (j != i0 && j != i1 && lo[j] > m2) m2 = lo[j];

    const float e1 = expf(m1 - m0);
    const float s0 = 1.f / (1.f + e1);
    const float s1 = e1 / (1.f + e1);
    out[(size_t)row * 2]             = (float)i0;
    out[(size_t)row * 2 + 1]         = (float)i1;
    out[16384 + (size_t)row * 2]     = s0;
    out[16384 + (size_t)row * 2 + 1] = s1;

    float cacc[32];
#pragma unroll
    for (int j = 0; j < 16; ++j) {
      cacc[j] = (j == i0) ? s0 : ((j == i1) ? s1 : 0.f);
      const bool in = ln[j] > m2;
      const float thr = in ? m2 : m1;
      const float z = (lg[j] - thr) / nc[j];
      cacc[16 + j] = 0.5f * (1.f + erff(z * 0.70710678118654752f));
    }
    // reduce the 32 loss partials across the 16 row-lanes
#pragma unroll
    for (int off = 1; off < 16; off <<= 1) {
#pragma unroll
      for (int k = 0; k < 32; ++k) cacc[k] += __shfl_xor(cacc[k], off, 16);
    }
    // lane t writes partial for expert t (static selection to avoid scratch)
    float v0 = 0.f, v1 = 0.f;
#pragma unroll
    for (int k = 0; k < 16; ++k) if (t == k) { v0 = cacc[k]; v1 = cacc[16 + k]; }
    part2[(size_t)rt * 32 + t]      = v0;
    part2[(size_t)rt * 32 + 16 + t] = v1;
  }
}

// ---------------- Kernel C: reduce per-block partials -> cv^2 loss ----------------
__global__ __launch_bounds__(256)
void gate_loss_k(const float* __restrict__ part2, float* __restrict__ out) {
  __shared__ float sred[8][32];
  const int t = threadIdx.x;        // 256
  const int k = t & 31, s = t >> 5; // expert, block-slice (8 slices of 64 blocks)
  float acc = 0.f;
#pragma unroll 8
  for (int i = 0; i < 64; ++i) acc += part2[(size_t)(s * 64 + i) * 32 + k];
  sred[s][k] = acc;
  __syncthreads();
  if (t == 0) {
    float res = 0.f;
    for (int g = 0; g < 2; ++g) {
      float vals[16];
      float mu = 0.f;
      for (int j = 0; j < 16; ++j) {
        float s2 = 0.f;
        for (int ss = 0; ss < 8; ++ss) s2 += sred[ss][g * 16 + j];
        vals[j] = s2;
        mu += s2;
      }
      mu *= (1.f / 16.f);
      float var = 0.f;
      for (int j = 0; j < 16; ++j) { const float d = vals[j] - mu; var += d * d; }
      var *= (1.f / 15.f);
      res += var / (mu * mu + 1e-10f);
    }
    out[32768] = res * 0.01f;
  }
}

extern "C" void kernel_launch(void* const* d_in, const int* in_sizes, int n_in,
                              void* d_out, int out_size, void* d_ws, size_t ws_size,
                              hipStream_t stream) {
  const float* x     = (const float*)d_in[0];
  const float* gw1   = (const float*)d_in[1];
  const float* gw2   = (const float*)d_in[2];
  const float* nw    = (const float*)d_in[3];
  const float* noise = (const float*)d_in[4];
  float* out   = (float*)d_out;
  u32*   wfrag = (u32*)d_ws;                                   // 768 KB, fully written
  float* part2 = (float*)((char*)d_ws + (size_t)768 * 1024);   // 64 KB, fully written
  split_w<<<128, 128, 0, stream>>>(gw1, nw, wfrag);
  gate_mega<<<512, 512, 0, stream>>>(x, wfrag, noise, gw2, out, part2);
  gate_loss_k<<<1, 256, 0, stream>>>(part2, out);
}

// Round 11
// 59.517 us; speedup vs baseline: 1.7215x; 1.0082x over previous
//
#include <hip/hip_runtime.h>
#include <math.h>

#define TT 8192
#define DD 4096

typedef float  f32x4  __attribute__((ext_vector_type(4)));
typedef short  bf16x8 __attribute__((ext_vector_type(8)));
typedef unsigned int u32;

// ---------------- Kernel P: split weights into 3 bf16 planes, frag-ordered ----------------
// wfrag word layout: ((p*128 + s)*2 + h)*256 + l*4  (uint4 per lane = 8 bf16)
// k = s*32 + (l>>4)*8 + i ; expert e = h*16 + (l&15).
__global__ __launch_bounds__(128)
void split_w(const float* __restrict__ gw1, const float* __restrict__ nw,
             u32* __restrict__ wfrag) {
  const int s = blockIdx.x;          // 128 k-steps
  const int t = threadIdx.x;
  const int h = t >> 6, l = t & 63;
  const int e = h * 16 + (l & 15);
  const float* src = ((e < 16) ? (gw1 + (size_t)e * DD) : (nw + (size_t)(e - 16) * DD))
                     + s * 32 + ((l >> 4) << 3);
  float f[8];
  *(float4*)&f[0] = *(const float4*)src;
  *(float4*)&f[4] = *(const float4*)(src + 4);
  u32 u0[8], u1[8], u2[8];
#pragma unroll
  for (int i = 0; i < 8; ++i) {
    u0[i] = __float_as_uint(f[i]);
    const float r1 = f[i] - __uint_as_float(u0[i] & 0xFFFF0000u);
    u1[i] = __float_as_uint(r1);
    const float r2 = r1 - __uint_as_float(u1[i] & 0xFFFF0000u);
    u2[i] = __float_as_uint(r2);
  }
  const size_t base = ((size_t)s * 2 + h) * 256 + l * 4;
#define PK(U) make_uint4((U[0]>>16)|(U[1]&0xFFFF0000u), (U[2]>>16)|(U[3]&0xFFFF0000u), \
                         (U[4]>>16)|(U[5]&0xFFFF0000u), (U[6]>>16)|(U[7]&0xFFFF0000u))
  *(uint4*)(wfrag + base)                 = PK(u0);
  *(uint4*)(wfrag + base + 128 * 512)     = PK(u1);   // plane stride = 128*2*256 words
  *(uint4*)(wfrag + base + 2 * 128 * 512) = PK(u2);
#undef PK
}

// ---------------- Kernel M: 32-rows-per-wave register blocking (B reuse x2) ----------------
// 256 blocks x 8 waves; block = 32 rows, wave w = k-slice w*512 over ALL 32 rows.
// Two 16-row A-fragments share the same 6 B-frags per iteration: 24 MFMA / 10 VMEM
// (vs 24 MFMA / 16 VMEM before). Chip-wide B traffic halves: 393 -> 196 MB.
// Rowsets sequenced in source to bound live VGPR. Plain loads, no pinning, no barriers
// in the loop (R1's free-flowing schedule). Each row's dot = same chain as all prior
// rounds (same elements -> same split -> same MFMA order -> same ascending reduce).
__global__ __launch_bounds__(512, 4)
void gate_mega(const float* __restrict__ x, const u32* __restrict__ wfrag,
               const float* __restrict__ noise, const float* __restrict__ gw2,
               float* __restrict__ out, float* __restrict__ part2) {
  __shared__ float red[8][1024];     // 32 KB: [slice][e*32 + row_in_block]
  __shared__ float sg2[256];
  const int t = threadIdx.x;
  const int w = t >> 6, l = t & 63;
  const int rt = blockIdx.x;         // 32-row tile 0..255
  if (t < 256) sg2[t] = gw2[t];

  const int r = l & 15, c = l >> 4;
  const float* xp0 = x + (size_t)(rt * 32 + r) * DD + w * 512 + (c << 3);
  const float* xp1 = xp0 + (size_t)16 * DD;
  const u32* wfl = wfrag + (size_t)l * 4 + (size_t)(w * 16) * 512;

  f32x4 g00 = {0,0,0,0}, g01 = g00, g02 = g00, n00 = g00, n01 = g00, n02 = g00;
  f32x4 g10 = g00, g11 = g00, g12 = g00, n10 = g00, n11 = g00, n12 = g00;

#define SPLIT8(FP, A0, A1, A2) \
  u32 pk_[12] __attribute__((aligned(16))); \
  { _Pragma("unroll") for (int p = 0; p < 4; ++p) { \
      const float fa = FP[2*p], fb = FP[2*p+1]; \
      const u32  a  = __float_as_uint(fa); \
      const float ra1 = fa - __uint_as_float(a & 0xFFFF0000u); \
      const u32  a1 = __float_as_uint(ra1); \
      const float ra2 = ra1 - __uint_as_float(a1 & 0xFFFF0000u); \
      const u32  a2 = __float_as_uint(ra2); \
      const u32  b  = __float_as_uint(fb); \
      const float rb1 = fb - __uint_as_float(b & 0xFFFF0000u); \
      const u32  b1 = __float_as_uint(rb1); \
      const float rb2 = rb1 - __uint_as_float(b1 & 0xFFFF0000u); \
      const u32  b2 = __float_as_uint(rb2); \
      pk_[p]     = (a  >> 16) | (b  & 0xFFFF0000u); \
      pk_[4 + p] = (a1 >> 16) | (b1 & 0xFFFF0000u); \
      pk_[8 + p] = (a2 >> 16) | (b2 & 0xFFFF0000u); } } \
  const bf16x8 A0 = *(const bf16x8*)&pk_[0]; \
  const bf16x8 A1 = *(const bf16x8*)&pk_[4]; \
  const bf16x8 A2 = *(const bf16x8*)&pk_[8];

#pragma unroll 2
  for (int sl = 0; sl < 16; ++sl) {
    const u32* wb = wfl + (size_t)sl * 512;
    const bf16x8 bg0 = *(const bf16x8*)(wb);
    const bf16x8 bn0 = *(const bf16x8*)(wb + 256);
    const bf16x8 bg1 = *(const bf16x8*)(wb + 128 * 512);
    const bf16x8 bn1 = *(const bf16x8*)(wb + 128 * 512 + 256);
    const bf16x8 bg2 = *(const bf16x8*)(wb + 2 * 128 * 512);
    const bf16x8 bn2 = *(const bf16x8*)(wb + 2 * 128 * 512 + 256);

    {   // rowset 0 (rows rt*32 + r)
      float f[8];
      *(float4*)&f[0] = *(const float4*)(xp0 + sl * 32);
      *(float4*)&f[4] = *(const float4*)(xp0 + sl * 32 + 4);
      SPLIT8(f, a0, a1, a2)
      g00 = __builtin_amdgcn_mfma_f32_16x16x32_bf16(a0, bg0, g00, 0, 0, 0);
      n00 = __builtin_amdgcn_mfma_f32_16x16x32_bf16(a0, bn0, n00, 0, 0, 0);
      g01 = __builtin_amdgcn_mfma_f32_16x16x32_bf16(a0, bg1, g01, 0, 0, 0);
      n01 = __builtin_amdgcn_mfma_f32_16x16x32_bf16(a0, bn1, n01, 0, 0, 0);
      g02 = __builtin_amdgcn_mfma_f32_16x16x32_bf16(a1, bg0, g02, 0, 0, 0);
      n02 = __builtin_amdgcn_mfma_f32_16x16x32_bf16(a1, bn0, n02, 0, 0, 0);
      g00 = __builtin_amdgcn_mfma_f32_16x16x32_bf16(a0, bg2, g00, 0, 0, 0);
      n00 = __builtin_amdgcn_mfma_f32_16x16x32_bf16(a0, bn2, n00, 0, 0, 0);
      g01 = __builtin_amdgcn_mfma_f32_16x16x32_bf16(a1, bg1, g01, 0, 0, 0);
      n01 = __builtin_amdgcn_mfma_f32_16x16x32_bf16(a1, bn1, n01, 0, 0, 0);
      g02 = __builtin_amdgcn_mfma_f32_16x16x32_bf16(a2, bg0, g02, 0, 0, 0);
      n02 = __builtin_amdgcn_mfma_f32_16x16x32_bf16(a2, bn0, n02, 0, 0, 0);
    }
    {   // rowset 1 (rows rt*32 + 16 + r), same B frags
      float f[8];
      *(float4*)&f[0] = *(const float4*)(xp1 + sl * 32);
      *(float4*)&f[4] = *(const float4*)(xp1 + sl * 32 + 4);
      SPLIT8(f, a0, a1, a2)
      g10 = __builtin_amdgcn_mfma_f32_16x16x32_bf16(a0, bg0, g10, 0, 0, 0);
      n10 = __builtin_amdgcn_mfma_f32_16x16x32_bf16(a0, bn0, n10, 0, 0, 0);
      g11 = __builtin_amdgcn_mfma_f32_16x16x32_bf16(a0, bg1, g11, 0, 0, 0);
      n11 = __builtin_amdgcn_mfma_f32_16x16x32_bf16(a0, bn1, n11, 0, 0, 0);
      g12 = __builtin_amdgcn_mfma_f32_16x16x32_bf16(a1, bg0, g12, 0, 0, 0);
      n12 = __builtin_amdgcn_mfma_f32_16x16x32_bf16(a1, bn0, n12, 0, 0, 0);
      g10 = __builtin_amdgcn_mfma_f32_16x16x32_bf16(a0, bg2, g10, 0, 0, 0);
      n10 = __builtin_amdgcn_mfma_f32_16x16x32_bf16(a0, bn2, n10, 0, 0, 0);
      g11 = __builtin_amdgcn_mfma_f32_16x16x32_bf16(a1, bg1, g11, 0, 0, 0);
      n11 = __builtin_amdgcn_mfma_f32_16x16x32_bf16(a1, bn1, n11, 0, 0, 0);
      g12 = __builtin_amdgcn_mfma_f32_16x16x32_bf16(a2, bg0, g12, 0, 0, 0);
      n12 = __builtin_amdgcn_mfma_f32_16x16x32_bf16(a2, bn0, n12, 0, 0, 0);
    }
  }
#undef SPLIT8

  const f32x4 cg0 = g00 + g01 + g02;
  const f32x4 cn0 = n00 + n01 + n02;
  const f32x4 cg1 = g10 + g11 + g12;
  const f32x4 cn1 = n10 + n11 + n12;
  // C/D: col(lane&15)=expert, row=(lane>>4)*4+reg [m89]. red[slice][e*32 + row_in_block].
#pragma unroll
  for (int j = 0; j < 4; ++j) {
    red[w][r * 32 + (c * 4 + j)]             = cg0[j];
    red[w][(16 + r) * 32 + (c * 4 + j)]      = cn0[j];
    red[w][r * 32 + 16 + (c * 4 + j)]        = cg1[j];
    red[w][(16 + r) * 32 + 16 + (c * 4 + j)] = cn1[j];
  }
  __syncthreads();
  // reduce across the 8 k-slices, ascending order; each column owned by one thread.
#pragma unroll
  for (int idx = t; idx < 1024; idx += 512) {
    float s = red[0][idx];
#pragma unroll
    for (int ww = 1; ww < 8; ++ww) s += red[ww][idx];
    red[0][idx] = s;
  }
  __syncthreads();

  if (t < 32) {
    const int row = rt * 32 + t;
    float dot[32];
#pragma unroll
    for (int e = 0; e < 32; ++e) dot[e] = red[0][e * 32 + t];
    float h[16];
#pragma unroll
    for (int e = 0; e < 16; ++e) h[e] = tanhf(dot[e]);
    float lg[16], nc[16], ln[16], lo[16];
#pragma unroll
    for (int j = 0; j < 16; ++j) {
      float s = 0.f;
#pragma unroll
      for (int e = 0; e < 16; ++e) s = fmaf(h[e], sg2[j * 16 + e], s);
      lg[j] = s;
      const float v = dot[16 + j];
      nc[j] = fmaxf(v, 0.f) + log1pf(expf(-fabsf(v))) + 0.01f;
      ln[j] = noise[(size_t)row * 16 + j] * nc[j];
      lo[j] = lg[j] + ln[j];
    }
    int i0 = 0; float m0 = lo[0];
#pragma unroll
    for (int j = 1; j < 16; ++j) if (lo[j] > m0) { m0 = lo[j]; i0 = j; }
    int i1 = -1; float m1 = -1e30f;
#pragma unroll
    for (int j = 0; j < 16; ++j) if (j != i0 && lo[j] > m1) { m1 = lo[j]; i1 = j; }
    float m2 = -1e30f;
#pragma unroll
    for (int j = 0; j < 16; ++j) if (j != i0 && j != i1 && lo[j] > m2) m2 = lo[j];

    const float e1 = expf(m1 - m0);
    const float s0 = 1.f / (1.f + e1);
    const float s1 = e1 / (1.f + e1);
    out[(size_t)row * 2]             = (float)i0;
    out[(size_t)row * 2 + 1]         = (float)i1;
    out[16384 + (size_t)row * 2]     = s0;
    out[16384 + (size_t)row * 2 + 1] = s1;

    float cacc[32];
#pragma unroll
    for (int j = 0; j < 16; ++j) {
      cacc[j] = (j == i0) ? s0 : ((j == i1) ? s1 : 0.f);
      const bool in = ln[j] > m2;
      const float thr = in ? m2 : m1;
      const float z = (lg[j] - thr) / nc[j];
      cacc[16 + j] = 0.5f * (1.f + erff(z * 0.70710678118654752f));
    }
    // reduce the 32 loss partials within each 16-row group (xor<16 stays in-group)
#pragma unroll
    for (int off = 1; off < 16; off <<= 1) {
#pragma unroll
      for (int k = 0; k < 32; ++k) cacc[k] += __shfl_xor(cacc[k], off, 16);
    }
    // group g = rt*2 + (t>>4): exact part2 layout/order of prior rounds (512 groups)
    const int g = rt * 2 + (t >> 4);
    const int rr = t & 15;
    float v0 = 0.f, v1 = 0.f;
#pragma unroll
    for (int k = 0; k < 16; ++k) if (rr == k) { v0 = cacc[k]; v1 = cacc[16 + k]; }
    part2[(size_t)g * 32 + rr]      = v0;
    part2[(size_t)g * 32 + 16 + rr] = v1;
  }
}

// ---------------- Kernel C: reduce per-block partials -> cv^2 loss ----------------
__global__ __launch_bounds__(256)
void gate_loss_k(const float* __restrict__ part2, float* __restrict__ out) {
  __shared__ float sred[8][32];
  const int t = threadIdx.x;        // 256
  const int k = t & 31, s = t >> 5; // expert, group-slice (8 slices of 64 groups)
  float acc = 0.f;
#pragma unroll 8
  for (int i = 0; i < 64; ++i) acc += part2[(size_t)(s * 64 + i) * 32 + k];
  sred[s][k] = acc;
  __syncthreads();
  if (t == 0) {
    float res = 0.f;
    for (int g = 0; g < 2; ++g) {
      float vals[16];
      float mu = 0.f;
      for (int j = 0; j < 16; ++j) {
        float s2 = 0.f;
        for (int ss = 0; ss < 8; ++ss) s2 += sred[ss][g * 16 + j];
        vals[j] = s2;
        mu += s2;
      }
      mu *= (1.f / 16.f);
      float var = 0.f;
      for (int j = 0; j < 16; ++j) { const float d = vals[j] - mu; var += d * d; }
      var *= (1.f / 15.f);
      res += var / (mu * mu + 1e-10f);
    }
    out[32768] = res * 0.01f;
  }
}

extern "C" void kernel_launch(void* const* d_in, const int* in_sizes, int n_in,
                              void* d_out, int out_size, void* d_ws, size_t ws_size,
                              hipStream_t stream) {
  const float* x     = (const float*)d_in[0];
  const float* gw1   = (const float*)d_in[1];
  const float* gw2   = (const float*)d_in[2];
  const float* nw    = (const float*)d_in[3];
  const float* noise = (const float*)d_in[4];
  float* out   = (float*)d_out;
  u32*   wfrag = (u32*)d_ws;                                   // 768 KB, fully written
  float* part2 = (float*)((char*)d_ws + (size_t)768 * 1024);   // 64 KB, fully written
  split_w<<<128, 128, 0, stream>>>(gw1, nw, wfrag);
  gate_mega<<<256, 512, 0, stream>>>(x, wfrag, noise, gw2, out, part2);
  gate_loss_k<<<1, 256, 0, stream>>>(part2, out);
}